// Round 11
// baseline (176.785 us; speedup 1.0000x reference)
//
#include <hip/hip_runtime.h>

// CausalSelfAttention: B=2, S=2048, D=1024, H=16, HD=64
#define B_  2
#define S_  2048
#define D_  1024
#define H_  16
#define HD_ 64
#define TD_ 3072
#define M_  (B_*S_)   // 4096
#define NWORK_ 24     // split-K items per plane: qi<8 -> 1 chunk, qi>=8 -> 2

using bf16x8 = __attribute__((ext_vector_type(8))) short;   // 8 bf16 = 4 VGPRs
using bf16x4 = __attribute__((ext_vector_type(4))) short;   // 4 bf16 = 2 VGPRs
using f32x4  = __attribute__((ext_vector_type(4))) float;   // MFMA C/D

typedef __attribute__((address_space(1))) unsigned int uint_g;
typedef __attribute__((address_space(3))) unsigned int uint_l;

#define MFMA32 __builtin_amdgcn_mfma_f32_16x16x32_bf16

#if defined(__has_builtin)
#if __has_builtin(__builtin_amdgcn_mfma_f32_16x16x16_bf16_1k)
#define MFMA16(a,b,c) __builtin_amdgcn_mfma_f32_16x16x16_bf16_1k(a,b,c,0,0,0)
#define HAVE_MFMA16 1
#elif __has_builtin(__builtin_amdgcn_mfma_f32_16x16x16bf16_1k)
#define MFMA16(a,b,c) __builtin_amdgcn_mfma_f32_16x16x16bf16_1k(a,b,c,0,0,0)
#define HAVE_MFMA16 1
#endif
#endif
#ifndef HAVE_MFMA16
static __device__ __forceinline__ f32x4 MFMA16_stub(bf16x4 a, bf16x4 b, f32x4 c) { return c; }
#define MFMA16(a,b,c) MFMA16_stub(a,b,c)   // parse-only (host pass)
#endif

static __device__ __forceinline__ short f2bf(float f) {
    unsigned u = __float_as_uint(f);
    u += 0x7FFFu + ((u >> 16) & 1u);   // round-to-nearest-even
    return (short)(u >> 16);
}
static __device__ __forceinline__ unsigned pack2bf(float a, float b) {
    return (unsigned)(unsigned short)f2bf(a) | ((unsigned)(unsigned short)f2bf(b) << 16);
}
// async global->LDS, 16B/lane; LDS dest = uniform base + lane*16 (m97/m104 semantics)
static __device__ __forceinline__ void gload_lds16(const short* g, short* l) {
    __builtin_amdgcn_global_load_lds((const uint_g*)g, (uint_l*)l, 16, 0, 0);
}
// unpack 8 bf16 (uint4) -> 8 floats
static __device__ __forceinline__ void unpack8(uint4 u, float* f) {
    unsigned a0 = u.x, a1 = u.y, a2 = u.z, a3 = u.w;
    f[0] = __uint_as_float(a0 << 16); f[1] = __uint_as_float(a0 & 0xFFFF0000u);
    f[2] = __uint_as_float(a1 << 16); f[3] = __uint_as_float(a1 & 0xFFFF0000u);
    f[4] = __uint_as_float(a2 << 16); f[5] = __uint_as_float(a2 & 0xFFFF0000u);
    f[6] = __uint_as_float(a3 << 16); f[7] = __uint_as_float(a3 & 0xFFFF0000u);
}

// ---------------------------------------------------------------------------
// Fused prep: block-range dispatch.
//   [0, 4096)    : cast x fp32 -> bf16
//   [4096, 7168) : wtrans w_attn [1024][3072] -> [3072][1024] bf16
//   [7168, 8192) : wtrans w_proj [1024][1024] -> [1024][1024] bf16
// ---------------------------------------------------------------------------
__global__ __launch_bounds__(256)
void prep_kernel(const float* __restrict__ x, short* __restrict__ xb,
                 const float* __restrict__ w_attn, short* __restrict__ wat,
                 const float* __restrict__ w_proj, short* __restrict__ wpt) {
    __shared__ float T[32][33];
    const int bx = blockIdx.x;
    if (bx < 4096) {
        int i = bx * 256 + threadIdx.x;
        float4 v = *((const float4*)x + i);
        short4 o;
        o.x = f2bf(v.x); o.y = f2bf(v.y); o.z = f2bf(v.z); o.w = f2bf(v.w);
        *((short4*)xb + i) = o;
        return;
    }
    const float* W; short* Wt; int N, n0, k0;
    if (bx < 7168) { int b = bx - 4096; W = w_attn; Wt = wat; N = TD_; n0 = (b % 96) * 32; k0 = (b / 96) * 32; }
    else           { int b = bx - 7168; W = w_proj; Wt = wpt; N = D_;  n0 = (b % 32) * 32; k0 = (b / 32) * 32; }
    const int tx = threadIdx.x & 31, ty = threadIdx.x >> 5;
    #pragma unroll
    for (int i = 0; i < 4; ++i)
        T[ty + i * 8][tx] = W[(size_t)(k0 + ty + i * 8) * N + n0 + tx];
    __syncthreads();
    #pragma unroll
    for (int i = 0; i < 4; ++i)
        Wt[(size_t)(n0 + ty + i * 8) * D_ + k0 + tx] = f2bf(T[tx][ty + i * 8]);
}

// ---------------------------------------------------------------------------
// GEMM1 (QKV projection): 128x128 tile, BK=32, 256 thr / 4 waves, 3-slot
// LDS ring (48KB -> 3 blocks/CU), counted vmcnt(4), st_16x32 swizzle
// both-sides, T5 setprio, bijective XCD swizzle (768 blocks). Verified R5/R7.
// Epilogue: scatter Q(scaled 0.125*log2e)/K bf16 [B,H,S,HD]; V pre-transposed
// to Vt [B,H,HD,S] (verified R8).
// ---------------------------------------------------------------------------
__global__ __launch_bounds__(256, 3)
void gemm128_qkv_kernel(const short* __restrict__ A, const short* __restrict__ Bt,
                        const float* __restrict__ bias,
                        short* __restrict__ Qo, short* __restrict__ Ko, short* __restrict__ Vto,
                        int M, int N, int K) {
    __shared__ __align__(16) char lds[49152];    // A slots @0 (24KB), B slots @24576

    const int tid  = threadIdx.x;
    const int w    = tid >> 6, lane = tid & 63;
    const int quad = lane >> 4, l16 = lane & 15;
    const int wm   = w >> 1,  wn  = w & 1;       // 2 x 2 waves

    const int gx  = gridDim.x;
    const int nwg = gx * gridDim.y;
    const int bid = blockIdx.y * gx + blockIdx.x;
    const int sbid = (bid & 7) * (nwg >> 3) + (bid >> 3);
    const int rowBase = (sbid / gx) * 128;
    const int colBase = (sbid % gx) * 128;

    const int scol = ((lane & 3) * 8) ^ ((lane & 32) >> 1);
    const int sr0  = w * 32 + (lane >> 2);
    const short* Asrc0 = A  + (size_t)(rowBase + sr0)      * K + scol;
    const short* Asrc1 = A  + (size_t)(rowBase + sr0 + 16) * K + scol;
    const short* Bsrc0 = Bt + (size_t)(colBase + sr0)      * K + scol;
    const short* Bsrc1 = Bt + (size_t)(colBase + sr0 + 16) * K + scol;

    const int rterm = (l16 * 64 + quad * 16) ^ ((l16 & 8) << 2);
    const char* ArdBase = lds + wm * 4096 + rterm;           // + mi*1024 + slot*8192
    const char* BrdBase = lds + 24576 + wn * 4096 + rterm;   // + ni*1024 + slot*8192

#define STAGE_A(t) { int sl_ = ((t) % 3) * 8192; \
    gload_lds16(Asrc0 + (size_t)(t) * 32, (short*)(lds + sl_) + (w * 2)     * 512); \
    gload_lds16(Asrc1 + (size_t)(t) * 32, (short*)(lds + sl_) + (w * 2 + 1) * 512); }
#define STAGE_B(t) { int sl_ = 24576 + ((t) % 3) * 8192; \
    gload_lds16(Bsrc0 + (size_t)(t) * 32, (short*)(lds + sl_) + (w * 2)     * 512); \
    gload_lds16(Bsrc1 + (size_t)(t) * 32, (short*)(lds + sl_) + (w * 2 + 1) * 512); }

    f32x4 acc[4][4];
    const f32x4 zero = {0.f, 0.f, 0.f, 0.f};
    #pragma unroll
    for (int i = 0; i < 4; ++i)
        #pragma unroll
        for (int j = 0; j < 4; ++j) acc[i][j] = zero;

    const int nk = K >> 5;                 // 32 K-tiles of BK=32
    STAGE_A(0); STAGE_B(0);
    STAGE_A(1); STAGE_B(1);

    for (int t = 0; t < nk; ++t) {
        if (t + 1 < nk) { asm volatile("s_waitcnt vmcnt(4)" ::: "memory"); }
        else            { asm volatile("s_waitcnt vmcnt(0)" ::: "memory"); }
        __builtin_amdgcn_s_barrier();
        __builtin_amdgcn_sched_barrier(0);

        const int sl = (t % 3) * 8192;
        const char* Ab = ArdBase + sl;
        const char* Bb = BrdBase + sl;
        bf16x8 bfr[4], afr[4];
        #pragma unroll
        for (int ni = 0; ni < 4; ++ni) bfr[ni] = *(const bf16x8*)(Bb + ni * 1024);
        #pragma unroll
        for (int mi = 0; mi < 4; ++mi) afr[mi] = *(const bf16x8*)(Ab + mi * 1024);
        if (t + 2 < nk) { STAGE_A(t + 2); STAGE_B(t + 2); }

        __builtin_amdgcn_s_setprio(1);
        #pragma unroll
        for (int mi = 0; mi < 4; ++mi)
            #pragma unroll
            for (int ni = 0; ni < 4; ++ni)
                acc[mi][ni] = MFMA32(afr[mi], bfr[ni], acc[mi][ni], 0, 0, 0);
        __builtin_amdgcn_s_setprio(0);
    }
#undef STAGE_A
#undef STAGE_B

    // epilogue: scatter Q/K as [B,H,S,HD]; V as [B,H,HD,S] (pre-transposed)
    #pragma unroll
    for (int ni = 0; ni < 4; ++ni) {
        int col = colBase + wn * 64 + ni * 16 + l16;
        int sel = col >> 10, cr = col & 1023;
        int h = cr >> 6, d = cr & 63;
        float bv  = bias[col];
        if (sel < 2) {
            short* dst = (sel == 0) ? Qo : Ko;
            float  scl = (sel == 0) ? 0.125f * 1.44269504f : 1.0f;  // 1/sqrt(64)*log2e
            #pragma unroll
            for (int mi = 0; mi < 4; ++mi) {
                int row = rowBase + wm * 64 + mi * 16 + quad * 4;
                #pragma unroll
                for (int r = 0; r < 4; ++r) {
                    int rw = row + r;
                    int bb = rw >> 11, s = rw & 2047;
                    dst[((size_t)(bb * H_ + h) * S_ + s) * HD_ + d] =
                        f2bf((acc[mi][ni][r] + bv) * scl);
                }
            }
        } else {
            #pragma unroll
            for (int mi = 0; mi < 4; ++mi) {
                int row = rowBase + wm * 64 + mi * 16 + quad * 4;
                int bb = row >> 11, s = row & 2047;
                uint2 o2;
                o2.x = pack2bf(acc[mi][ni][0] + bv, acc[mi][ni][1] + bv);
                o2.y = pack2bf(acc[mi][ni][2] + bv, acc[mi][ni][3] + bv);
                *(uint2*)(Vto + ((size_t)(bb * H_ + h) * HD_ + d) * S_ + s) = o2;
            }
        }
    }
}

// ---------------------------------------------------------------------------
// GEMM2 (out-proj): 128x128 tile, BK=32, 256 thr / 4 waves. 4-slot ring
// (64KB), counted vmcnt(4), st_16x32 swizzle both-sides, T5 setprio.
// Grid 8x32 = 256 blocks. fp32 C + bias epilogue. (Verified R4/R5/R7/R8;
// PINNED: the 128x64 split is -3.2us, isolated-tested R10.)
// ---------------------------------------------------------------------------
__global__ __launch_bounds__(256, 2)
void gemm128_ring_kernel(const short* __restrict__ A, const short* __restrict__ Bt,
                         const float* __restrict__ bias, float* __restrict__ Cf,
                         int M, int N, int K) {
    __shared__ __align__(16) char lds[65536];    // A slots @0, B slots @32768

    const int tid  = threadIdx.x;
    const int w    = tid >> 6, lane = tid & 63;
    const int quad = lane >> 4, l16 = lane & 15;
    const int wm   = w >> 1,  wn  = w & 1;       // 2 x 2 waves

    const int gx  = gridDim.x;
    const int nwg = gx * gridDim.y;
    const int bid = blockIdx.y * gx + blockIdx.x;
    const int sbid = (bid & 7) * (nwg >> 3) + (bid >> 3);
    const int rowBase = (sbid / gx) * 128;
    const int colBase = (sbid % gx) * 128;

    const int scol = ((lane & 3) * 8) ^ ((lane & 32) >> 1);   // inverse swizzle
    const int sr0  = w * 32 + (lane >> 2);
    const short* Asrc0 = A  + (size_t)(rowBase + sr0)      * K + scol;
    const short* Asrc1 = A  + (size_t)(rowBase + sr0 + 16) * K + scol;
    const short* Bsrc0 = Bt + (size_t)(colBase + sr0)      * K + scol;
    const short* Bsrc1 = Bt + (size_t)(colBase + sr0 + 16) * K + scol;

    const int rterm = (l16 * 64 + quad * 16) ^ ((l16 & 8) << 2);
    const char* ArdBase = lds + wm * 4096 + rterm;           // + mi*1024 + slot*8192
    const char* BrdBase = lds + 32768 + wn * 4096 + rterm;   // + ni*1024 + slot*8192

#define STAGE_A(t) { int sl_ = ((t) & 3) * 8192; \
    gload_lds16(Asrc0 + (size_t)(t) * 32, (short*)(lds + sl_) + (w * 2)     * 512); \
    gload_lds16(Asrc1 + (size_t)(t) * 32, (short*)(lds + sl_) + (w * 2 + 1) * 512); }
#define STAGE_B(t) { int sl_ = 32768 + ((t) & 3) * 8192; \
    gload_lds16(Bsrc0 + (size_t)(t) * 32, (short*)(lds + sl_) + (w * 2)     * 512); \
    gload_lds16(Bsrc1 + (size_t)(t) * 32, (short*)(lds + sl_) + (w * 2 + 1) * 512); }

    f32x4 acc[4][4];
    const f32x4 zero = {0.f, 0.f, 0.f, 0.f};
    #pragma unroll
    for (int i = 0; i < 4; ++i)
        #pragma unroll
        for (int j = 0; j < 4; ++j) acc[i][j] = zero;

    const int nk = K >> 5;                 // 32 K-tiles of BK=32
    STAGE_A(0); STAGE_B(0);
    STAGE_A(1); STAGE_B(1);

    for (int t = 0; t < nk; ++t) {
        if (t + 1 < nk) { asm volatile("s_waitcnt vmcnt(4)" ::: "memory"); }
        else            { asm volatile("s_waitcnt vmcnt(0)" ::: "memory"); }
        __builtin_amdgcn_s_barrier();
        __builtin_amdgcn_sched_barrier(0);

        const char* Ab = ArdBase + (t & 3) * 8192;
        const char* Bb = BrdBase + (t & 3) * 8192;
        bf16x8 bfr[4], afr[4];
        #pragma unroll
        for (int ni = 0; ni < 4; ++ni) bfr[ni] = *(const bf16x8*)(Bb + ni * 1024);
        #pragma unroll
        for (int mi = 0; mi < 4; ++mi) afr[mi] = *(const bf16x8*)(Ab + mi * 1024);
        if (t + 2 < nk) { STAGE_A(t + 2); STAGE_B(t + 2); }

        __builtin_amdgcn_s_setprio(1);
        #pragma unroll
        for (int mi = 0; mi < 4; ++mi)
            #pragma unroll
            for (int ni = 0; ni < 4; ++ni)
                acc[mi][ni] = MFMA32(afr[mi], bfr[ni], acc[mi][ni], 0, 0, 0);
        __builtin_amdgcn_s_setprio(0);
    }
#undef STAGE_A
#undef STAGE_B

    // epilogue: fp32 C + bias
    #pragma unroll
    for (int mi = 0; mi < 4; ++mi) {
        int row = rowBase + wm * 64 + mi * 16 + quad * 4;
        #pragma unroll
        for (int ni = 0; ni < 4; ++ni) {
            int col = colBase + wn * 64 + ni * 16 + l16;
            float bv = bias[col];
            #pragma unroll
            for (int r = 0; r < 4; ++r)
                Cf[(size_t)(row + r) * N + col] = acc[mi][ni][r] + bv;
        }
    }
}

// ---------------------------------------------------------------------------
// Split-K MFMA causal flash attention v12: GEMM-style 3-slot LDS ring with
// global_load_lds staging. Per KV tile (64 wide): 4 gload calls (K:2, V:2),
// counted vmcnt(4) (tile t+1 stays in flight across the barrier), ONE
// barrier per tile. No VGPR prefetch (R9's spill eliminated by design).
// Bank-conflict fix (rule #21 both-sides): linear LDS dest + pre-swizzled
// global source chunk ((lane&7)^(lane>>3)) + chunk^(row&7) on ds_read.
// Slot: K [64][64] @0, V [64][64] @4096 (shorts); 3 slots = 48KB -> 3/CU.
// y<8: full causal range -> normalize in-register, store direct to atb.
// y>=8: unnormalized partials (pO, pl).
// ---------------------------------------------------------------------------
__global__ __launch_bounds__(256, 3)
void flash_mfma_kernel(const short* __restrict__ Qg, const short* __restrict__ Kg,
                       const short* __restrict__ Vtg,
                       short* __restrict__ pO, float* __restrict__ pl,
                       short* __restrict__ atb) {
    __shared__ __align__(16) short KV[3][8192];

    const int plane_id = blockIdx.x;             // b*H + h
    const int y = blockIdx.y;                    // work item 0..23
    int qi, kc;
    if (y < 8) { qi = y; kc = 0; }
    else       { qi = 8 + ((y - 8) >> 1); kc = (y - 8) & 1; }
    int nkt = 2 * qi + 2 - kc * 16;
    if (nkt > 16) nkt = 16;
    const int kvOrigin = kc * 1024;

    const int tid  = threadIdx.x;
    const int w    = tid >> 6, lane = tid & 63;
    const int quad = lane >> 4, l16 = lane & 15;
    const int qBase = qi * 128;
    const size_t plane = (size_t)plane_id * S_ * HD_;

    // staging geometry: wave w covers rows w*8+(lane>>3) (+32 for 2nd call),
    // source col chunk pre-swizzled: (lane&7)^(lane>>3) (row&7 == lane>>3).
    const int srow = w * 8 + (lane >> 3);        // 0..31
    const int swz8 = (((lane & 7) ^ (lane >> 3))) * 8;   // shorts

#define FSTAGE(t) { short* sb_ = &KV[(t) % 3][0]; \
    const int kvB_ = kvOrigin + (t) * 64; \
    gload_lds16(Kg  + plane + (size_t)(kvB_ + srow)      * HD_ + swz8, sb_ + (w * 8) * 64); \
    gload_lds16(Kg  + plane + (size_t)(kvB_ + srow + 32) * HD_ + swz8, sb_ + (32 + w * 8) * 64); \
    gload_lds16(Vtg + plane + (size_t)srow        * S_ + kvB_ + swz8, sb_ + 4096 + (w * 8) * 64); \
    gload_lds16(Vtg + plane + (size_t)(srow + 32) * S_ + kvB_ + swz8, sb_ + 4096 + (32 + w * 8) * 64); }

    // Q B-frags for both subtiles (pre-scaled by 0.125*log2e at GEMM1 epilogue)
    const int qsubA = qBase + w * 32;            // subtile A rows [qsubA, +16)
    const short* QrowA = Qg + plane + (size_t)(qsubA + l16) * HD_ + quad * 8;
    const bf16x8 qa0 = *(const bf16x8*)(QrowA);
    const bf16x8 qa1 = *(const bf16x8*)(QrowA + 32);
    const short* QrowB = QrowA + 16 * HD_;       // subtile B rows [qsubA+16, +16)
    const bf16x8 qb0 = *(const bf16x8*)(QrowB);
    const bf16x8 qb1 = *(const bf16x8*)(QrowB + 32);

    f32x4 oA[4], oB[4];
    const f32x4 zero = {0.f, 0.f, 0.f, 0.f};
    #pragma unroll
    for (int i = 0; i < 4; ++i) { oA[i] = zero; oB[i] = zero; }
    float lA = 0.f, lB = 0.f;
    const int q_globA = qsubA + l16;
    const int q_globB = qsubA + 16 + l16;
    const int q_wave_max = qsubA + 31;

    // K read swizzle terms (row = ct*16+l16 -> row&7 == l16&7)
    const int l7 = l16 & 7;

    FSTAGE(0);
    if (nkt > 1) FSTAGE(1);

    for (int j = 0; j < nkt; ++j) {
        if (j + 1 < nkt) { asm volatile("s_waitcnt vmcnt(4)" ::: "memory"); }
        else             { asm volatile("s_waitcnt vmcnt(0)" ::: "memory"); }
        __builtin_amdgcn_s_barrier();
        __builtin_amdgcn_sched_barrier(0);

        const short* sb = &KV[j % 3][0];
        if (j + 2 < nkt) FSTAGE(j + 2);

        const int kvBase = kvOrigin + j * 64;
        if (kvBase > q_wave_max) continue;     // wave above diagonal (no more barriers needed this iter)

        // ---- S^T = K Q^T for BOTH subtiles: each kf read feeds 2 MFMAs
        f32x4 sA[4], sB[4];
        __builtin_amdgcn_s_setprio(1);
        #pragma unroll
        for (int ct = 0; ct < 4; ++ct) {
            const short* Krow = sb + (ct * 16 + l16) * 64;
            bf16x8 kf0 = *(const bf16x8*)(Krow + (quad ^ l7) * 8);
            bf16x8 kf1 = *(const bf16x8*)(Krow + ((4 + quad) ^ l7) * 8);
            f32x4 a = zero, b = zero;
            a = MFMA32(kf0, qa0, a, 0, 0, 0);
            a = MFMA32(kf1, qa1, a, 0, 0, 0);
            b = MFMA32(kf0, qb0, b, 0, 0, 0);
            b = MFMA32(kf1, qb1, b, 0, 0, 0);
            sA[ct] = a; sB[ct] = b;
        }
        __builtin_amdgcn_s_setprio(0);

        // ---- causal mask per subtile (only near the diagonal)
        if (kvBase + 63 > qsubA) {
            #pragma unroll
            for (int ct = 0; ct < 4; ++ct) {
                int kv = kvBase + ct * 16 + quad * 4;
                #pragma unroll
                for (int r = 0; r < 4; ++r)
                    if (kv + r > q_globA) sA[ct][r] = -3.0e38f;
            }
        }
        if (kvBase + 63 > qsubA + 16) {
            #pragma unroll
            for (int ct = 0; ct < 4; ++ct) {
                int kv = kvBase + ct * 16 + quad * 4;
                #pragma unroll
                for (int r = 0; r < 4; ++r)
                    if (kv + r > q_globB) sB[ct][r] = -3.0e38f;
            }
        }

        // ---- no-max softmax + PV: S already in log2 domain -> raw exp2
        #pragma unroll
        for (int ct = 0; ct < 4; ++ct) {
            float pa0 = __builtin_amdgcn_exp2f(sA[ct][0]), pa1 = __builtin_amdgcn_exp2f(sA[ct][1]);
            float pa2 = __builtin_amdgcn_exp2f(sA[ct][2]), pa3 = __builtin_amdgcn_exp2f(sA[ct][3]);
            float pb0 = __builtin_amdgcn_exp2f(sB[ct][0]), pb1 = __builtin_amdgcn_exp2f(sB[ct][1]);
            float pb2 = __builtin_amdgcn_exp2f(sB[ct][2]), pb3 = __builtin_amdgcn_exp2f(sB[ct][3]);
            lA += (pa0 + pa1) + (pa2 + pa3);
            lB += (pb0 + pb1) + (pb2 + pb3);
            bf16x4 pA, pB;
            *(unsigned*)&pA       = pack2bf(pa0, pa1);
            *((unsigned*)&pA + 1) = pack2bf(pa2, pa3);
            *(unsigned*)&pB       = pack2bf(pb0, pb1);
            *((unsigned*)&pB + 1) = pack2bf(pb2, pb3);
            __builtin_amdgcn_s_setprio(1);
            #pragma unroll
            for (int dt = 0; dt < 4; ++dt) {
                // V[row=dt*16+l16][col=ct*16+quad*4]: 16B chunk = 2ct+(quad>>1),
                // swizzled ^ (row&7)=l7; +4-short sub-offset for odd quads.
                const short* Vrow = sb + 4096 + (dt * 16 + l16) * 64;
                bf16x4 vfr = *(const bf16x4*)(Vrow + ((2 * ct + (quad >> 1)) ^ l7) * 8 + (quad & 1) * 4);
                oA[dt] = MFMA16(vfr, pA, oA[dt]);
                oB[dt] = MFMA16(vfr, pB, oB[dt]);
            }
            __builtin_amdgcn_s_setprio(0);
        }
    }

    // ---- l reduce over quads: after xor(16)+xor(32) EVERY lane holds the
    // full row sum for its q row (col = l16 of subtile A / B).
    lA += __shfl_xor(lA, 16); lA += __shfl_xor(lA, 32);
    lB += __shfl_xor(lB, 16); lB += __shfl_xor(lB, 32);

    __syncthreads();                       // all LDS readers done before reuse
    short* Pw = &KV[0][0] + w * 2304;      // per-wave 32x72 transpose buffer

    if (y < 8) {
        // full causal range covered -> normalize in-register, store to atb
        const float invA = 1.0f / lA, invB = 1.0f / lB;
        #pragma unroll
        for (int dt = 0; dt < 4; ++dt) {
            uint2 ua, ub;
            ua.x = pack2bf(oA[dt][0] * invA, oA[dt][1] * invA);
            ua.y = pack2bf(oA[dt][2] * invA, oA[dt][3] * invA);
            ub.x = pack2bf(oB[dt][0] * invB, oB[dt][1] * invB);
            ub.y = pack2bf(oB[dt][2] * invB, oB[dt][3] * invB);
            *(uint2*)&Pw[l16 * 72 + dt * 16 + quad * 4]        = ua;  // [q_loc][d]
            *(uint2*)&Pw[(16 + l16) * 72 + dt * 16 + quad * 4] = ub;
        }
        __builtin_amdgcn_s_waitcnt(0xC07F);    // lgkmcnt(0)
        const int b = plane_id >> 4, h = plane_id & (H_ - 1);
        short* outBase = atb + (size_t)(b * S_ + qBase + w * 32) * D_ + h * HD_;
        #pragma unroll
        for (int pass = 0; pass < 4; ++pass) {
            int r  = pass * 8 + (lane >> 3);   // 0..31
            int cs = (lane & 7) * 8;
            uint4 vv = *(const uint4*)&Pw[r * 72 + cs];
            *(uint4*)(outBase + (size_t)r * D_ + cs) = vv;
        }
        return;
    }

    // ---- y>=8: partial path
    const size_t lbase = ((size_t)plane_id * NWORK_ + y) * 128 + w * 32;
    if (quad == 0) {
        pl[lbase + l16]      = lA;
        pl[lbase + 16 + l16] = lB;
    }

    #pragma unroll
    for (int dt = 0; dt < 4; ++dt) {
        uint2 ua, ub;
        ua.x = pack2bf(oA[dt][0], oA[dt][1]);
        ua.y = pack2bf(oA[dt][2], oA[dt][3]);
        ub.x = pack2bf(oB[dt][0], oB[dt][1]);
        ub.y = pack2bf(oB[dt][2], oB[dt][3]);
        *(uint2*)&Pw[l16 * 72 + dt * 16 + quad * 4]        = ua;  // [q_loc][d]
        *(uint2*)&Pw[(16 + l16) * 72 + dt * 16 + quad * 4] = ub;
    }
    __builtin_amdgcn_s_waitcnt(0xC07F);    // lgkmcnt(0): own-wave writes done
    short* outBase = pO + (((size_t)plane_id * NWORK_ + y) * 128 + w * 32) * 64;
    #pragma unroll
    for (int pass = 0; pass < 4; ++pass) {
        int r  = pass * 8 + (lane >> 3);   // 0..31
        int cs = (lane & 7) * 8;
        uint4 vv = *(const uint4*)&Pw[r * 72 + cs];
        *(uint4*)(outBase + r * 64 + cs) = vv;
    }
#undef FSTAGE
}

// ---------------------------------------------------------------------------
// Reduce split-K partials for qi in [8,16) only (y<8 writes atb direct):
// atb[q][h*64+d] = (O_part0 + O_part1) / (l_part0 + l_part1)
// ---------------------------------------------------------------------------
__global__ __launch_bounds__(256)
void reduce_kernel(const short* __restrict__ pO, const float* __restrict__ pl,
                   short* __restrict__ atb) {
    const int plane_id = blockIdx.x, qi = 8 + blockIdx.y;
    const int h = plane_id & (H_ - 1), b = plane_id >> 4;
    const int tid = threadIdx.x;
    const int row = tid >> 1;              // 0..127
    const int cb  = (tid & 1) * 32;        // 0 or 32

    const int t0 = 8 + 2 * (qi - 8);       // always two chunks

    const size_t pbase = (((size_t)plane_id * NWORK_ + t0) * 128 + row) * 64 + cb;
    float f[32], g[8];
    unpack8(*(const uint4*)(pO + pbase),      f);
    unpack8(*(const uint4*)(pO + pbase + 8),  f + 8);
    unpack8(*(const uint4*)(pO + pbase + 16), f + 16);
    unpack8(*(const uint4*)(pO + pbase + 24), f + 24);
    float l = pl[((size_t)plane_id * NWORK_ + t0) * 128 + row];
    #pragma unroll
    for (int c = 0; c < 4; ++c) {
        unpack8(*(const uint4*)(pO + pbase + 8192 + c * 8), g);
        #pragma unroll
        for (int i = 0; i < 8; ++i) f[c * 8 + i] += g[i];
    }
    l += pl[((size_t)plane_id * NWORK_ + t0 + 1) * 128 + row];

    const float inv = 1.0f / l;
    short* dst = atb + (size_t)(b * S_ + qi * 128 + row) * D_ + h * HD_ + cb;
    #pragma unroll
    for (int c = 0; c < 4; ++c) {
        uint2 o2;
        o2.x = pack2bf(f[c * 8 + 0] * inv, f[c * 8 + 1] * inv);
        o2.y = pack2bf(f[c * 8 + 2] * inv, f[c * 8 + 3] * inv);
        uint2 o3;
        o3.x = pack2bf(f[c * 8 + 4] * inv, f[c * 8 + 5] * inv);
        o3.y = pack2bf(f[c * 8 + 6] * inv, f[c * 8 + 7] * inv);
        uint4 ov; ov.x = o2.x; ov.y = o2.y; ov.z = o3.x; ov.w = o3.y;
        *(uint4*)(dst + c * 8) = ov;
    }
}

// ---------------------------------------------------------------------------
extern "C" void kernel_launch(void* const* d_in, const int* in_sizes, int n_in,
                              void* d_out, int out_size, void* d_ws, size_t ws_size,
                              hipStream_t stream) {
    const float* x      = (const float*)d_in[0];
    const float* w_attn = (const float*)d_in[1];
    const float* b_attn = (const float*)d_in[2];
    const float* w_proj = (const float*)d_in[3];
    const float* b_proj = (const float*)d_in[4];
    float* out = (float*)d_out;

    char* ws = (char*)d_ws;
    short* xb  = (short*)ws; ws += (size_t)M_ * D_ * 2;    // dead after gemm1
    short* wat = (short*)ws; ws += (size_t)TD_ * D_ * 2;   // dead after gemm1
    short* wpt = (short*)ws; ws += (size_t)D_ * D_ * 2;
    short* qg  = (short*)ws; ws += (size_t)M_ * D_ * 2;
    short* kg  = (short*)ws; ws += (size_t)M_ * D_ * 2;
    short* vg  = (short*)ws; ws += (size_t)M_ * D_ * 2;    // unused (V goes direct to vtg)
    short* vtg = (short*)ws; ws += (size_t)M_ * D_ * 2;
    short* atb = (short*)ws; ws += (size_t)M_ * D_ * 2;

    // split-K partials overlay the dead xb+wat region (12.97 MB < 14 MB)
    short* pO = (short*)d_ws;                                           // 12.58 MB
    float* pl = (float*)((char*)d_ws + (size_t)32 * NWORK_ * 128 * 64 * 2); // 0.39 MB

    prep_kernel<<<8192, 256, 0, stream>>>(x, xb, w_attn, wat, w_proj, wpt);

    // GEMM1 writes V directly transposed into vtg -> no vtrans dispatch
    gemm128_qkv_kernel<<<dim3(TD_ / 128, M_ / 128), 256, 0, stream>>>(
        xb, wat, b_attn, qg, kg, vtg, M_, TD_, D_);

    // plane fastest (32 % 8 == 0): each plane's blocks pin to one XCD (L2 reuse)
    flash_mfma_kernel<<<dim3(B_ * H_, NWORK_), 256, 0, stream>>>(qg, kg, vtg, pO, pl, atb);

    reduce_kernel<<<dim3(B_ * H_, 8), 256, 0, stream>>>(pO, pl, atb);

    gemm128_ring_kernel<<<dim3(D_ / 128, M_ / 128), 256, 0, stream>>>(
        atb, wpt, b_proj, out, M_, D_, D_);
}

// Round 12
// 164.060 us; speedup vs baseline: 1.0776x; 1.0776x over previous
//
#include <hip/hip_runtime.h>

// CausalSelfAttention: B=2, S=2048, D=1024, H=16, HD=64
#define B_  2
#define S_  2048
#define D_  1024
#define H_  16
#define HD_ 64
#define TD_ 3072
#define M_  (B_*S_)   // 4096
#define NWORK_ 24     // split-K items per plane: qi<8 -> 1 chunk, qi>=8 -> 2

using bf16x8 = __attribute__((ext_vector_type(8))) short;   // 8 bf16 = 4 VGPRs
using bf16x4 = __attribute__((ext_vector_type(4))) short;   // 4 bf16 = 2 VGPRs
using f32x4  = __attribute__((ext_vector_type(4))) float;   // MFMA C/D

typedef __attribute__((address_space(1))) unsigned int uint_g;
typedef __attribute__((address_space(3))) unsigned int uint_l;

#define MFMA32 __builtin_amdgcn_mfma_f32_16x16x32_bf16

#if defined(__has_builtin)
#if __has_builtin(__builtin_amdgcn_mfma_f32_16x16x16_bf16_1k)
#define MFMA16(a,b,c) __builtin_amdgcn_mfma_f32_16x16x16_bf16_1k(a,b,c,0,0,0)
#define HAVE_MFMA16 1
#elif __has_builtin(__builtin_amdgcn_mfma_f32_16x16x16bf16_1k)
#define MFMA16(a,b,c) __builtin_amdgcn_mfma_f32_16x16x16bf16_1k(a,b,c,0,0,0)
#define HAVE_MFMA16 1
#endif
#endif
#ifndef HAVE_MFMA16
static __device__ __forceinline__ f32x4 MFMA16_stub(bf16x4 a, bf16x4 b, f32x4 c) { return c; }
#define MFMA16(a,b,c) MFMA16_stub(a,b,c)   // parse-only (host pass)
#endif

static __device__ __forceinline__ short f2bf(float f) {
    unsigned u = __float_as_uint(f);
    u += 0x7FFFu + ((u >> 16) & 1u);   // round-to-nearest-even
    return (short)(u >> 16);
}
static __device__ __forceinline__ unsigned pack2bf(float a, float b) {
    return (unsigned)(unsigned short)f2bf(a) | ((unsigned)(unsigned short)f2bf(b) << 16);
}
// async global->LDS, 16B/lane; LDS dest = uniform base + lane*16 (m97/m104 semantics)
static __device__ __forceinline__ void gload_lds16(const short* g, short* l) {
    __builtin_amdgcn_global_load_lds((const uint_g*)g, (uint_l*)l, 16, 0, 0);
}
// unpack 8 bf16 (uint4) -> 8 floats
static __device__ __forceinline__ void unpack8(uint4 u, float* f) {
    unsigned a0 = u.x, a1 = u.y, a2 = u.z, a3 = u.w;
    f[0] = __uint_as_float(a0 << 16); f[1] = __uint_as_float(a0 & 0xFFFF0000u);
    f[2] = __uint_as_float(a1 << 16); f[3] = __uint_as_float(a1 & 0xFFFF0000u);
    f[4] = __uint_as_float(a2 << 16); f[5] = __uint_as_float(a2 & 0xFFFF0000u);
    f[6] = __uint_as_float(a3 << 16); f[7] = __uint_as_float(a3 & 0xFFFF0000u);
}

// ---------------------------------------------------------------------------
// Fused prep: block-range dispatch.
//   [0, 4096)    : cast x fp32 -> bf16
//   [4096, 7168) : wtrans w_attn [1024][3072] -> [3072][1024] bf16
//   [7168, 8192) : wtrans w_proj [1024][1024] -> [1024][1024] bf16
// ---------------------------------------------------------------------------
__global__ __launch_bounds__(256)
void prep_kernel(const float* __restrict__ x, short* __restrict__ xb,
                 const float* __restrict__ w_attn, short* __restrict__ wat,
                 const float* __restrict__ w_proj, short* __restrict__ wpt) {
    __shared__ float T[32][33];
    const int bx = blockIdx.x;
    if (bx < 4096) {
        int i = bx * 256 + threadIdx.x;
        float4 v = *((const float4*)x + i);
        short4 o;
        o.x = f2bf(v.x); o.y = f2bf(v.y); o.z = f2bf(v.z); o.w = f2bf(v.w);
        *((short4*)xb + i) = o;
        return;
    }
    const float* W; short* Wt; int N, n0, k0;
    if (bx < 7168) { int b = bx - 4096; W = w_attn; Wt = wat; N = TD_; n0 = (b % 96) * 32; k0 = (b / 96) * 32; }
    else           { int b = bx - 7168; W = w_proj; Wt = wpt; N = D_;  n0 = (b % 32) * 32; k0 = (b / 32) * 32; }
    const int tx = threadIdx.x & 31, ty = threadIdx.x >> 5;
    #pragma unroll
    for (int i = 0; i < 4; ++i)
        T[ty + i * 8][tx] = W[(size_t)(k0 + ty + i * 8) * N + n0 + tx];
    __syncthreads();
    #pragma unroll
    for (int i = 0; i < 4; ++i)
        Wt[(size_t)(n0 + ty + i * 8) * D_ + k0 + tx] = f2bf(T[tx][ty + i * 8]);
}

// ---------------------------------------------------------------------------
// GEMM1 (QKV projection): 128x128 tile, BK=32, 256 thr / 4 waves, 3-slot
// LDS ring (48KB -> 3 blocks/CU), counted vmcnt(4), st_16x32 swizzle
// both-sides, T5 setprio, bijective XCD swizzle (768 blocks). Verified R5/R7.
// Epilogue: scatter Q(scaled 0.125*log2e)/K bf16 [B,H,S,HD]; V pre-transposed
// to Vt [B,H,HD,S] (verified R8).
// ---------------------------------------------------------------------------
__global__ __launch_bounds__(256, 3)
void gemm128_qkv_kernel(const short* __restrict__ A, const short* __restrict__ Bt,
                        const float* __restrict__ bias,
                        short* __restrict__ Qo, short* __restrict__ Ko, short* __restrict__ Vto,
                        int M, int N, int K) {
    __shared__ __align__(16) char lds[49152];    // A slots @0 (24KB), B slots @24576

    const int tid  = threadIdx.x;
    const int w    = tid >> 6, lane = tid & 63;
    const int quad = lane >> 4, l16 = lane & 15;
    const int wm   = w >> 1,  wn  = w & 1;       // 2 x 2 waves

    const int gx  = gridDim.x;
    const int nwg = gx * gridDim.y;
    const int bid = blockIdx.y * gx + blockIdx.x;
    const int sbid = (bid & 7) * (nwg >> 3) + (bid >> 3);
    const int rowBase = (sbid / gx) * 128;
    const int colBase = (sbid % gx) * 128;

    const int scol = ((lane & 3) * 8) ^ ((lane & 32) >> 1);
    const int sr0  = w * 32 + (lane >> 2);
    const short* Asrc0 = A  + (size_t)(rowBase + sr0)      * K + scol;
    const short* Asrc1 = A  + (size_t)(rowBase + sr0 + 16) * K + scol;
    const short* Bsrc0 = Bt + (size_t)(colBase + sr0)      * K + scol;
    const short* Bsrc1 = Bt + (size_t)(colBase + sr0 + 16) * K + scol;

    const int rterm = (l16 * 64 + quad * 16) ^ ((l16 & 8) << 2);
    const char* ArdBase = lds + wm * 4096 + rterm;           // + mi*1024 + slot*8192
    const char* BrdBase = lds + 24576 + wn * 4096 + rterm;   // + ni*1024 + slot*8192

#define STAGE_A(t) { int sl_ = ((t) % 3) * 8192; \
    gload_lds16(Asrc0 + (size_t)(t) * 32, (short*)(lds + sl_) + (w * 2)     * 512); \
    gload_lds16(Asrc1 + (size_t)(t) * 32, (short*)(lds + sl_) + (w * 2 + 1) * 512); }
#define STAGE_B(t) { int sl_ = 24576 + ((t) % 3) * 8192; \
    gload_lds16(Bsrc0 + (size_t)(t) * 32, (short*)(lds + sl_) + (w * 2)     * 512); \
    gload_lds16(Bsrc1 + (size_t)(t) * 32, (short*)(lds + sl_) + (w * 2 + 1) * 512); }

    f32x4 acc[4][4];
    const f32x4 zero = {0.f, 0.f, 0.f, 0.f};
    #pragma unroll
    for (int i = 0; i < 4; ++i)
        #pragma unroll
        for (int j = 0; j < 4; ++j) acc[i][j] = zero;

    const int nk = K >> 5;                 // 32 K-tiles of BK=32
    STAGE_A(0); STAGE_B(0);
    STAGE_A(1); STAGE_B(1);

    for (int t = 0; t < nk; ++t) {
        if (t + 1 < nk) { asm volatile("s_waitcnt vmcnt(4)" ::: "memory"); }
        else            { asm volatile("s_waitcnt vmcnt(0)" ::: "memory"); }
        __builtin_amdgcn_s_barrier();
        __builtin_amdgcn_sched_barrier(0);

        const int sl = (t % 3) * 8192;
        const char* Ab = ArdBase + sl;
        const char* Bb = BrdBase + sl;
        bf16x8 bfr[4], afr[4];
        #pragma unroll
        for (int ni = 0; ni < 4; ++ni) bfr[ni] = *(const bf16x8*)(Bb + ni * 1024);
        #pragma unroll
        for (int mi = 0; mi < 4; ++mi) afr[mi] = *(const bf16x8*)(Ab + mi * 1024);
        if (t + 2 < nk) { STAGE_A(t + 2); STAGE_B(t + 2); }

        __builtin_amdgcn_s_setprio(1);
        #pragma unroll
        for (int mi = 0; mi < 4; ++mi)
            #pragma unroll
            for (int ni = 0; ni < 4; ++ni)
                acc[mi][ni] = MFMA32(afr[mi], bfr[ni], acc[mi][ni], 0, 0, 0);
        __builtin_amdgcn_s_setprio(0);
    }
#undef STAGE_A
#undef STAGE_B

    // epilogue: scatter Q/K as [B,H,S,HD]; V as [B,H,HD,S] (pre-transposed)
    #pragma unroll
    for (int ni = 0; ni < 4; ++ni) {
        int col = colBase + wn * 64 + ni * 16 + l16;
        int sel = col >> 10, cr = col & 1023;
        int h = cr >> 6, d = cr & 63;
        float bv  = bias[col];
        if (sel < 2) {
            short* dst = (sel == 0) ? Qo : Ko;
            float  scl = (sel == 0) ? 0.125f * 1.44269504f : 1.0f;  // 1/sqrt(64)*log2e
            #pragma unroll
            for (int mi = 0; mi < 4; ++mi) {
                int row = rowBase + wm * 64 + mi * 16 + quad * 4;
                #pragma unroll
                for (int r = 0; r < 4; ++r) {
                    int rw = row + r;
                    int bb = rw >> 11, s = rw & 2047;
                    dst[((size_t)(bb * H_ + h) * S_ + s) * HD_ + d] =
                        f2bf((acc[mi][ni][r] + bv) * scl);
                }
            }
        } else {
            #pragma unroll
            for (int mi = 0; mi < 4; ++mi) {
                int row = rowBase + wm * 64 + mi * 16 + quad * 4;
                int bb = row >> 11, s = row & 2047;
                uint2 o2;
                o2.x = pack2bf(acc[mi][ni][0] + bv, acc[mi][ni][1] + bv);
                o2.y = pack2bf(acc[mi][ni][2] + bv, acc[mi][ni][3] + bv);
                *(uint2*)(Vto + ((size_t)(bb * H_ + h) * HD_ + d) * S_ + s) = o2;
            }
        }
    }
}

// ---------------------------------------------------------------------------
// GEMM2 (out-proj): 128x128 tile, BK=32, 256 thr / 4 waves. 4-slot ring
// (64KB), counted vmcnt(4), st_16x32 swizzle both-sides, T5 setprio.
// Grid 8x32 = 256 blocks. fp32 C + bias epilogue. (Verified; PINNED R10.)
// ---------------------------------------------------------------------------
__global__ __launch_bounds__(256, 2)
void gemm128_ring_kernel(const short* __restrict__ A, const short* __restrict__ Bt,
                         const float* __restrict__ bias, float* __restrict__ Cf,
                         int M, int N, int K) {
    __shared__ __align__(16) char lds[65536];    // A slots @0, B slots @32768

    const int tid  = threadIdx.x;
    const int w    = tid >> 6, lane = tid & 63;
    const int quad = lane >> 4, l16 = lane & 15;
    const int wm   = w >> 1,  wn  = w & 1;       // 2 x 2 waves

    const int gx  = gridDim.x;
    const int nwg = gx * gridDim.y;
    const int bid = blockIdx.y * gx + blockIdx.x;
    const int sbid = (bid & 7) * (nwg >> 3) + (bid >> 3);
    const int rowBase = (sbid / gx) * 128;
    const int colBase = (sbid % gx) * 128;

    const int scol = ((lane & 3) * 8) ^ ((lane & 32) >> 1);   // inverse swizzle
    const int sr0  = w * 32 + (lane >> 2);
    const short* Asrc0 = A  + (size_t)(rowBase + sr0)      * K + scol;
    const short* Asrc1 = A  + (size_t)(rowBase + sr0 + 16) * K + scol;
    const short* Bsrc0 = Bt + (size_t)(colBase + sr0)      * K + scol;
    const short* Bsrc1 = Bt + (size_t)(colBase + sr0 + 16) * K + scol;

    const int rterm = (l16 * 64 + quad * 16) ^ ((l16 & 8) << 2);
    const char* ArdBase = lds + wm * 4096 + rterm;           // + mi*1024 + slot*8192
    const char* BrdBase = lds + 32768 + wn * 4096 + rterm;   // + ni*1024 + slot*8192

#define STAGE_A(t) { int sl_ = ((t) & 3) * 8192; \
    gload_lds16(Asrc0 + (size_t)(t) * 32, (short*)(lds + sl_) + (w * 2)     * 512); \
    gload_lds16(Asrc1 + (size_t)(t) * 32, (short*)(lds + sl_) + (w * 2 + 1) * 512); }
#define STAGE_B(t) { int sl_ = 32768 + ((t) & 3) * 8192; \
    gload_lds16(Bsrc0 + (size_t)(t) * 32, (short*)(lds + sl_) + (w * 2)     * 512); \
    gload_lds16(Bsrc1 + (size_t)(t) * 32, (short*)(lds + sl_) + (w * 2 + 1) * 512); }

    f32x4 acc[4][4];
    const f32x4 zero = {0.f, 0.f, 0.f, 0.f};
    #pragma unroll
    for (int i = 0; i < 4; ++i)
        #pragma unroll
        for (int j = 0; j < 4; ++j) acc[i][j] = zero;

    const int nk = K >> 5;                 // 32 K-tiles of BK=32
    STAGE_A(0); STAGE_B(0);
    STAGE_A(1); STAGE_B(1);

    for (int t = 0; t < nk; ++t) {
        if (t + 1 < nk) { asm volatile("s_waitcnt vmcnt(4)" ::: "memory"); }
        else            { asm volatile("s_waitcnt vmcnt(0)" ::: "memory"); }
        __builtin_amdgcn_s_barrier();
        __builtin_amdgcn_sched_barrier(0);

        const char* Ab = ArdBase + (t & 3) * 8192;
        const char* Bb = BrdBase + (t & 3) * 8192;
        bf16x8 bfr[4], afr[4];
        #pragma unroll
        for (int ni = 0; ni < 4; ++ni) bfr[ni] = *(const bf16x8*)(Bb + ni * 1024);
        #pragma unroll
        for (int mi = 0; mi < 4; ++mi) afr[mi] = *(const bf16x8*)(Ab + mi * 1024);
        if (t + 2 < nk) { STAGE_A(t + 2); STAGE_B(t + 2); }

        __builtin_amdgcn_s_setprio(1);
        #pragma unroll
        for (int mi = 0; mi < 4; ++mi)
            #pragma unroll
            for (int ni = 0; ni < 4; ++ni)
                acc[mi][ni] = MFMA32(afr[mi], bfr[ni], acc[mi][ni], 0, 0, 0);
        __builtin_amdgcn_s_setprio(0);
    }
#undef STAGE_A
#undef STAGE_B

    // epilogue: fp32 C + bias
    #pragma unroll
    for (int mi = 0; mi < 4; ++mi) {
        int row = rowBase + wm * 64 + mi * 16 + quad * 4;
        #pragma unroll
        for (int ni = 0; ni < 4; ++ni) {
            int col = colBase + wn * 64 + ni * 16 + l16;
            float bv = bias[col];
            #pragma unroll
            for (int r = 0; r < 4; ++r)
                Cf[(size_t)(row + r) * N + col] = acc[mi][ni][r] + bv;
        }
    }
}

// ---------------------------------------------------------------------------
// Split-K MFMA causal flash attention (R8-verified body; R11's gload-ring
// reverted — it measured 42.4us vs R8's ~40).
// NEW (isolated): load-balance permutation ymap[]. With 768 blocks = 3/CU
// round-robin (block n -> CU n%256), a CU hosts work items {y, y+8, y+16};
// raw triple sums range 16..46 tiles (3x imbalance). ymap pairs the ten
// 16-tile items with complements so EVERY triple sums to 34.
// Pure permutation: correctness-neutral.
// ---------------------------------------------------------------------------
__global__ __launch_bounds__(256, 3)
void flash_mfma_kernel(const short* __restrict__ Qg, const short* __restrict__ Kg,
                       const short* __restrict__ Vtg,
                       short* __restrict__ pO, float* __restrict__ pl,
                       short* __restrict__ atb) {
    __shared__ __align__(16) short Ks[64][72];
    __shared__ __align__(16) short Vs[64][72];   // Vs[d][kv]

    const int plane_id = blockIdx.x;             // b*H + h
    // balanced work-item map: triples {g, g+8, g+16} sum to 34 tiles each
    const int ymap[24] = { 7, 10, 14, 16, 18, 20, 22, 23,
                           8, 12,  6, 21,  5, 19,  4, 17,
                           0,  9,  1, 11,  2, 13,  3, 15 };
    const int y = ymap[blockIdx.y];              // work item 0..23
    int qi, kc;
    if (y < 8) { qi = y; kc = 0; }
    else       { qi = 8 + ((y - 8) >> 1); kc = (y - 8) & 1; }
    int nkt = 2 * qi + 2 - kc * 16;
    if (nkt > 16) nkt = 16;
    const int kvOrigin = kc * 1024;

    const int tid  = threadIdx.x;
    const int w    = tid >> 6, lane = tid & 63;
    const int quad = lane >> 4, l16 = lane & 15;
    const int qBase = qi * 128;
    const size_t plane = (size_t)plane_id * S_ * HD_;

    // staging: thread covers rows sr0 and sr0+32, cols sc0..sc0+7 (shorts)
    const int sr0 = tid >> 3;          // 0..31
    const int sc0 = (tid & 7) * 8;

    // Q B-frags for both subtiles (pre-scaled by 0.125*log2e at GEMM1 epilogue)
    const int qsubA = qBase + w * 32;            // subtile A rows [qsubA, +16)
    const short* QrowA = Qg + plane + (size_t)(qsubA + l16) * HD_ + quad * 8;
    const bf16x8 qa0 = *(const bf16x8*)(QrowA);
    const bf16x8 qa1 = *(const bf16x8*)(QrowA + 32);
    const short* QrowB = QrowA + 16 * HD_;       // subtile B rows [qsubA+16, +16)
    const bf16x8 qb0 = *(const bf16x8*)(QrowB);
    const bf16x8 qb1 = *(const bf16x8*)(QrowB + 32);

    f32x4 oA[4], oB[4];
    const f32x4 zero = {0.f, 0.f, 0.f, 0.f};
    #pragma unroll
    for (int i = 0; i < 4; ++i) { oA[i] = zero; oB[i] = zero; }
    float lA = 0.f, lB = 0.f;
    const int q_globA = qsubA + l16;
    const int q_globB = qsubA + 16 + l16;
    const int q_wave_max = qsubA + 31;

    // prefetch tile j=0
    uint4 ka0, ka1, va0, va1;
    ka0 = *(const uint4*)(Kg  + plane + (size_t)(kvOrigin + sr0)      * HD_ + sc0);
    ka1 = *(const uint4*)(Kg  + plane + (size_t)(kvOrigin + sr0 + 32) * HD_ + sc0);
    va0 = *(const uint4*)(Vtg + plane + (size_t)sr0        * S_ + kvOrigin + sc0);
    va1 = *(const uint4*)(Vtg + plane + (size_t)(sr0 + 32) * S_ + kvOrigin + sc0);

    for (int j = 0; j < nkt; ++j) {
        __syncthreads();                   // prev iter's LDS reads done
        *(uint4*)&Ks[sr0][sc0]      = ka0; // implicit vmcnt wait
        *(uint4*)&Ks[sr0 + 32][sc0] = ka1;
        *(uint4*)&Vs[sr0][sc0]      = va0;
        *(uint4*)&Vs[sr0 + 32][sc0] = va1;
        __syncthreads();                   // tile visible to all waves

        if (j + 1 < nkt) {                 // issue next-tile loads now
            const int kvB = kvOrigin + (j + 1) * 64;
            ka0 = *(const uint4*)(Kg  + plane + (size_t)(kvB + sr0)      * HD_ + sc0);
            ka1 = *(const uint4*)(Kg  + plane + (size_t)(kvB + sr0 + 32) * HD_ + sc0);
            va0 = *(const uint4*)(Vtg + plane + (size_t)sr0        * S_ + kvB + sc0);
            va1 = *(const uint4*)(Vtg + plane + (size_t)(sr0 + 32) * S_ + kvB + sc0);
        }

        const int kvBase = kvOrigin + j * 64;
        if (kvBase > q_wave_max) continue;     // wave entirely above diagonal

        // ---- S^T = K Q^T for BOTH subtiles: each kf read feeds 2 MFMAs
        f32x4 sA[4], sB[4];
        __builtin_amdgcn_s_setprio(1);
        #pragma unroll
        for (int ct = 0; ct < 4; ++ct) {
            bf16x8 kf0 = *(const bf16x8*)&Ks[ct * 16 + l16][quad * 8];
            bf16x8 kf1 = *(const bf16x8*)&Ks[ct * 16 + l16][32 + quad * 8];
            f32x4 a = zero, b = zero;
            a = MFMA32(kf0, qa0, a, 0, 0, 0);
            a = MFMA32(kf1, qa1, a, 0, 0, 0);
            b = MFMA32(kf0, qb0, b, 0, 0, 0);
            b = MFMA32(kf1, qb1, b, 0, 0, 0);
            sA[ct] = a; sB[ct] = b;
        }
        __builtin_amdgcn_s_setprio(0);

        // ---- causal mask per subtile (only near the diagonal)
        if (kvBase + 63 > qsubA) {
            #pragma unroll
            for (int ct = 0; ct < 4; ++ct) {
                int kv = kvBase + ct * 16 + quad * 4;
                #pragma unroll
                for (int r = 0; r < 4; ++r)
                    if (kv + r > q_globA) sA[ct][r] = -3.0e38f;
            }
        }
        if (kvBase + 63 > qsubA + 16) {
            #pragma unroll
            for (int ct = 0; ct < 4; ++ct) {
                int kv = kvBase + ct * 16 + quad * 4;
                #pragma unroll
                for (int r = 0; r < 4; ++r)
                    if (kv + r > q_globB) sB[ct][r] = -3.0e38f;
            }
        }

        // ---- no-max softmax + PV: S already in log2 domain -> raw exp2
        #pragma unroll
        for (int ct = 0; ct < 4; ++ct) {
            float pa0 = __builtin_amdgcn_exp2f(sA[ct][0]), pa1 = __builtin_amdgcn_exp2f(sA[ct][1]);
            float pa2 = __builtin_amdgcn_exp2f(sA[ct][2]), pa3 = __builtin_amdgcn_exp2f(sA[ct][3]);
            float pb0 = __builtin_amdgcn_exp2f(sB[ct][0]), pb1 = __builtin_amdgcn_exp2f(sB[ct][1]);
            float pb2 = __builtin_amdgcn_exp2f(sB[ct][2]), pb3 = __builtin_amdgcn_exp2f(sB[ct][3]);
            lA += (pa0 + pa1) + (pa2 + pa3);
            lB += (pb0 + pb1) + (pb2 + pb3);
            bf16x4 pA, pB;
            *(unsigned*)&pA       = pack2bf(pa0, pa1);
            *((unsigned*)&pA + 1) = pack2bf(pa2, pa3);
            *(unsigned*)&pB       = pack2bf(pb0, pb1);
            *((unsigned*)&pB + 1) = pack2bf(pb2, pb3);
            __builtin_amdgcn_s_setprio(1);
            #pragma unroll
            for (int dt = 0; dt < 4; ++dt) {
                bf16x4 vfr = *(const bf16x4*)&Vs[dt * 16 + l16][ct * 16 + quad * 4];
                oA[dt] = MFMA16(vfr, pA, oA[dt]);
                oB[dt] = MFMA16(vfr, pB, oB[dt]);
            }
            __builtin_amdgcn_s_setprio(0);
        }
    }

    // ---- l reduce over quads: after xor(16)+xor(32) EVERY lane holds the
    // full row sum for its q row (col = l16 of subtile A / B).
    lA += __shfl_xor(lA, 16); lA += __shfl_xor(lA, 32);
    lB += __shfl_xor(lB, 16); lB += __shfl_xor(lB, 32);

    if (y < 8) {
        // full causal range covered -> normalize in-register, store to atb
        const float invA = 1.0f / lA, invB = 1.0f / lB;
        __syncthreads();                   // all K/V readers done before reuse
        short* Pw = (w < 2) ? &Ks[w * 32][0] : &Vs[(w - 2) * 32][0];
        #pragma unroll
        for (int dt = 0; dt < 4; ++dt) {
            uint2 ua, ub;
            ua.x = pack2bf(oA[dt][0] * invA, oA[dt][1] * invA);
            ua.y = pack2bf(oA[dt][2] * invA, oA[dt][3] * invA);
            ub.x = pack2bf(oB[dt][0] * invB, oB[dt][1] * invB);
            ub.y = pack2bf(oB[dt][2] * invB, oB[dt][3] * invB);
            *(uint2*)&Pw[l16 * 72 + dt * 16 + quad * 4]        = ua;  // [q_loc][d]
            *(uint2*)&Pw[(16 + l16) * 72 + dt * 16 + quad * 4] = ub;
        }
        __builtin_amdgcn_s_waitcnt(0xC07F);    // lgkmcnt(0)
        const int b = plane_id >> 4, h = plane_id & (H_ - 1);
        short* outBase = atb + (size_t)(b * S_ + qBase + w * 32) * D_ + h * HD_;
        #pragma unroll
        for (int pass = 0; pass < 4; ++pass) {
            int r  = pass * 8 + (lane >> 3);   // 0..31
            int cs = (lane & 7) * 8;
            uint4 vv = *(const uint4*)&Pw[r * 72 + cs];
            *(uint4*)(outBase + (size_t)r * D_ + cs) = vv;
        }
        return;
    }

    // ---- y>=8: partial path
    const size_t lbase = ((size_t)plane_id * NWORK_ + y) * 128 + w * 32;
    if (quad == 0) {
        pl[lbase + l16]      = lA;
        pl[lbase + 16 + l16] = lB;
    }

    __syncthreads();                       // all K/V readers done before reuse
    short* Pw = (w < 2) ? &Ks[w * 32][0] : &Vs[(w - 2) * 32][0];
    #pragma unroll
    for (int dt = 0; dt < 4; ++dt) {
        uint2 ua, ub;
        ua.x = pack2bf(oA[dt][0], oA[dt][1]);
        ua.y = pack2bf(oA[dt][2], oA[dt][3]);
        ub.x = pack2bf(oB[dt][0], oB[dt][1]);
        ub.y = pack2bf(oB[dt][2], oB[dt][3]);
        *(uint2*)&Pw[l16 * 72 + dt * 16 + quad * 4]        = ua;  // [q_loc][d]
        *(uint2*)&Pw[(16 + l16) * 72 + dt * 16 + quad * 4] = ub;
    }
    __builtin_amdgcn_s_waitcnt(0xC07F);    // lgkmcnt(0): own-wave writes done
    short* outBase = pO + (((size_t)plane_id * NWORK_ + y) * 128 + w * 32) * 64;
    #pragma unroll
    for (int pass = 0; pass < 4; ++pass) {
        int r  = pass * 8 + (lane >> 3);   // 0..31
        int cs = (lane & 7) * 8;
        uint4 vv = *(const uint4*)&Pw[r * 72 + cs];
        *(uint4*)(outBase + r * 64 + cs) = vv;
    }
}

// ---------------------------------------------------------------------------
// Reduce split-K partials for qi in [8,16) only (y<8 writes atb direct):
// atb[q][h*64+d] = (O_part0 + O_part1) / (l_part0 + l_part1)
// ---------------------------------------------------------------------------
__global__ __launch_bounds__(256)
void reduce_kernel(const short* __restrict__ pO, const float* __restrict__ pl,
                   short* __restrict__ atb) {
    const int plane_id = blockIdx.x, qi = 8 + blockIdx.y;
    const int h = plane_id & (H_ - 1), b = plane_id >> 4;
    const int tid = threadIdx.x;
    const int row = tid >> 1;              // 0..127
    const int cb  = (tid & 1) * 32;        // 0 or 32

    const int t0 = 8 + 2 * (qi - 8);       // always two chunks

    const size_t pbase = (((size_t)plane_id * NWORK_ + t0) * 128 + row) * 64 + cb;
    float f[32], g[8];
    unpack8(*(const uint4*)(pO + pbase),      f);
    unpack8(*(const uint4*)(pO + pbase + 8),  f + 8);
    unpack8(*(const uint4*)(pO + pbase + 16), f + 16);
    unpack8(*(const uint4*)(pO + pbase + 24), f + 24);
    float l = pl[((size_t)plane_id * NWORK_ + t0) * 128 + row];
    #pragma unroll
    for (int c = 0; c < 4; ++c) {
        unpack8(*(const uint4*)(pO + pbase + 8192 + c * 8), g);
        #pragma unroll
        for (int i = 0; i < 8; ++i) f[c * 8 + i] += g[i];
    }
    l += pl[((size_t)plane_id * NWORK_ + t0 + 1) * 128 + row];

    const float inv = 1.0f / l;
    short* dst = atb + (size_t)(b * S_ + qi * 128 + row) * D_ + h * HD_ + cb;
    #pragma unroll
    for (int c = 0; c < 4; ++c) {
        uint2 o2;
        o2.x = pack2bf(f[c * 8 + 0] * inv, f[c * 8 + 1] * inv);
        o2.y = pack2bf(f[c * 8 + 2] * inv, f[c * 8 + 3] * inv);
        uint2 o3;
        o3.x = pack2bf(f[c * 8 + 4] * inv, f[c * 8 + 5] * inv);
        o3.y = pack2bf(f[c * 8 + 6] * inv, f[c * 8 + 7] * inv);
        uint4 ov; ov.x = o2.x; ov.y = o2.y; ov.z = o3.x; ov.w = o3.y;
        *(uint4*)(dst + c * 8) = ov;
    }
}

// ---------------------------------------------------------------------------
extern "C" void kernel_launch(void* const* d_in, const int* in_sizes, int n_in,
                              void* d_out, int out_size, void* d_ws, size_t ws_size,
                              hipStream_t stream) {
    const float* x      = (const float*)d_in[0];
    const float* w_attn = (const float*)d_in[1];
    const float* b_attn = (const float*)d_in[2];
    const float* w_proj = (const float*)d_in[3];
    const float* b_proj = (const float*)d_in[4];
    float* out = (float*)d_out;

    char* ws = (char*)d_ws;
    short* xb  = (short*)ws; ws += (size_t)M_ * D_ * 2;    // dead after gemm1
    short* wat = (short*)ws; ws += (size_t)TD_ * D_ * 2;   // dead after gemm1
    short* wpt = (short*)ws; ws += (size_t)D_ * D_ * 2;
    short* qg  = (short*)ws; ws += (size_t)M_ * D_ * 2;
    short* kg  = (short*)ws; ws += (size_t)M_ * D_ * 2;
    short* vg  = (short*)ws; ws += (size_t)M_ * D_ * 2;    // unused (V goes direct to vtg)
    short* vtg = (short*)ws; ws += (size_t)M_ * D_ * 2;
    short* atb = (short*)ws; ws += (size_t)M_ * D_ * 2;

    // split-K partials overlay the dead xb+wat region (12.97 MB < 14 MB)
    short* pO = (short*)d_ws;                                           // 12.58 MB
    float* pl = (float*)((char*)d_ws + (size_t)32 * NWORK_ * 128 * 64 * 2); // 0.39 MB

    prep_kernel<<<8192, 256, 0, stream>>>(x, xb, w_attn, wat, w_proj, wpt);

    // GEMM1 writes V directly transposed into vtg -> no vtrans dispatch
    gemm128_qkv_kernel<<<dim3(TD_ / 128, M_ / 128), 256, 0, stream>>>(
        xb, wat, b_attn, qg, kg, vtg, M_, TD_, D_);

    // plane fastest (32 % 8 == 0): each plane's blocks pin to one XCD (L2 reuse)
    flash_mfma_kernel<<<dim3(B_ * H_, NWORK_), 256, 0, stream>>>(qg, kg, vtg, pO, pl, atb);

    reduce_kernel<<<dim3(B_ * H_, 8), 256, 0, stream>>>(pO, pl, atb);

    gemm128_ring_kernel<<<dim3(D_ / 128, M_ / 128), 256, 0, stream>>>(
        atb, wpt, b_proj, out, M_, D_, D_);
}